// Round 12
// baseline (177.196 us; speedup 1.0000x reference)
//
#include <hip/hip_runtime.h>
#include <math.h>

#define B_ 8
#define T_ 100
#define S_ 400
#define H_ 256
#define HQ_ (H_ / 4)
#define BT_ (B_ * T_)
#define MAXL 30.0f
#define K_EXP 2.885390081777927f   // 2*log2(e): exp2(K*z) = e^(2z)

#define AF_OFF (BT_ * H_)
#define LOSS_OFF (BT_ * H_ + BT_ * S_)

// ws layout (floats) — exp-domain
#define EWHT_OFF 0                        // EWhT4 [B][H/4][S][4] = exp2(K*Wh)
#define EWSB_OFF (B_ * H_ * S_)           // EWsb [BT][H] = exp2(K*(Ws+b))
#define ACOV_OFF (EWSB_OFF + BT_ * H_)    // A / cov [BT][S] (in-place scan)

// exp2 Taylor (quartic): exp2(x) = 1 + x(c1 + x(c2 + x(c3 + x*c4)))
#define EC1 0.6931471806f
#define EC2 0.2402265070f
#define EC3 0.0555041087f
#define EC4 0.0096181291f

__device__ __forceinline__ float wave_sum(float p) {
#pragma unroll
    for (int off = 32; off; off >>= 1) p += __shfl_xor(p, off, 64);
    return p;
}

__device__ __forceinline__ float wave_max(float p) {
#pragma unroll
    for (int off = 32; off; off >>= 1) p = fmaxf(p, __shfl_xor(p, off, 64));
    return p;
}

// ---------------- K1: EWhT4 (quad-interleaved), EWsb -------------------------
#define ROWS 8
__global__ __launch_bounds__(256) void k_gemm(
    const float* __restrict__ dec, const float* __restrict__ enc,
    const float* __restrict__ W_h, const float* __restrict__ W_s,
    const float* __restrict__ b_attn,
    float* __restrict__ EWhT4, float* __restrict__ EWsb) {
    const int tid = threadIdx.x;          // output h
    const int blk = blockIdx.x;
    const int NB_ENC = (B_ * S_) / ROWS;  // 400

    float acc[ROWS];
#pragma unroll
    for (int r = 0; r < ROWS; ++r) acc[r] = 0.f;

    if (blk < NB_ENC) {
        const int r0 = blk * ROWS;            // 8 enc rows, same b
        const int b = r0 / S_, s0 = r0 - b * S_;
        const float* in = enc + (size_t)r0 * H_;   // block-uniform -> s_loads
        const float* Wp = W_h + tid;
#pragma unroll 4
        for (int h = 0; h < H_; ++h) {
            float w = Wp[(size_t)h * H_];
#pragma unroll
            for (int r = 0; r < ROWS; ++r)
                acc[r] = fmaf(in[r * H_ + h], w, acc[r]);
        }
        float* o = EWhT4 + (((size_t)b * HQ_ + (tid >> 2)) * S_ + s0) * 4 + (tid & 3);
#pragma unroll
        for (int r = 0; r < ROWS; ++r)
            o[r * 4] = __builtin_amdgcn_exp2f(K_EXP * acc[r]);
    } else {
        const int bt0 = (blk - NB_ENC) * ROWS;
        const float* in = dec + (size_t)bt0 * H_;
        const float* Wp = W_s + tid;
        const float bias = b_attn[tid];
#pragma unroll 4
        for (int h = 0; h < H_; ++h) {
            float w = Wp[(size_t)h * H_];
#pragma unroll
            for (int r = 0; r < ROWS; ++r)
                acc[r] = fmaf(in[r * H_ + h], w, acc[r]);
        }
#pragma unroll
        for (int r = 0; r < ROWS; ++r)
            EWsb[(size_t)(bt0 + r) * H_ + tid] =
                __builtin_amdgcn_exp2f(K_EXP * (acc[r] + bias));
    }
}

// ---------------- K2: prelim logits + softmax (t-pair block, 1024 thr) -------
// 16 waves/block (6.25 waves/SIMD); thread = (t-parity, s).
__global__ __launch_bounds__(1024) void k_prelim(
    const float* __restrict__ EWhT4, const float* __restrict__ EWsb,
    const float* __restrict__ v,
    const unsigned char* __restrict__ mask,
    float* __restrict__ A) {
    __shared__ float red[32];
    const int blk = blockIdx.x;
    const int b = blk & 7;
    const int tp = blk >> 3;
    const int tid = threadIdx.x;
    const int hh = tid >> 9;          // 0/1 -> which t of the pair
    const int s = tid & 511;
    const int bt = b * T_ + 2 * tp + hh;
    const int lane = tid & 63;
    const int wid = tid >> 6;         // 0..15 (0-7 are hh=0)
    const bool act = (s < S_);

    const float4 vv4 = *reinterpret_cast<const float4*>(v + 4 * lane);
    const float sumv = wave_sum((vv4.x + vv4.y) + (vv4.z + vv4.w));

    const float* E = EWsb + (size_t)bt * H_;   // wave-uniform -> s_loads
    float acc = 0.f;
    if (act) {
        const float4* eq = reinterpret_cast<const float4*>(
                               EWhT4 + (size_t)b * HQ_ * S_ * 4) + s;
#pragma unroll 4
        for (int hq = 0; hq < HQ_; ++hq) {
            const float4 Ew = eq[(size_t)hq * S_];
            const int h = 4 * hq;
            const float v0 = v[h], v1 = v[h + 1], v2 = v[h + 2], v3 = v[h + 3];
            float p0 = fmaf(Ew.x, E[h], 1.f);
            float p1 = fmaf(Ew.y, E[h + 1], 1.f);
            float p2 = fmaf(Ew.z, E[h + 2], 1.f);
            float p3 = fmaf(Ew.w, E[h + 3], 1.f);
            float p01 = p0 * p1, p23 = p2 * p3;
            float num = fmaf(fmaf(v0, p1, v1 * p0), p23,
                             fmaf(v2, p3, v3 * p2) * p01);
            acc = fmaf(num, __builtin_amdgcn_rcpf(p01 * p23), acc);
        }
    }

    float e = -INFINITY;
    if (act) {
        e = fminf(fmaxf(sumv - 2.f * acc, -MAXL), MAXL);
        if (mask[(size_t)b * S_ + s]) e = -INFINITY;
    }

    float mx = wave_max(e);
    if (lane == 0) red[wid] = mx;
    __syncthreads();
    {
        const float* r8 = red + 8 * hh;
        mx = fmaxf(fmaxf(fmaxf(r8[0], r8[1]), fmaxf(r8[2], r8[3])),
                   fmaxf(fmaxf(r8[4], r8[5]), fmaxf(r8[6], r8[7])));
    }

    float p = act ? __expf(e - mx) : 0.f;
    float sm = wave_sum(p);
    if (lane == 0) red[16 + wid] = sm;
    __syncthreads();
    {
        const float* r8 = red + 16 + 8 * hh;
        sm = ((r8[0] + r8[1]) + (r8[2] + r8[3])) +
             ((r8[4] + r8[5]) + (r8[6] + r8[7]));
    }

    if (act) A[(size_t)bt * S_ + s] = p * __builtin_amdgcn_rcpf(sm);
}

// ---------------- K3: in-place exclusive scan over t; zero loss --------------
__global__ __launch_bounds__(64) void k_cumsum(float* __restrict__ A,
                                               float* __restrict__ out) {
    const int idx = blockIdx.x * 64 + threadIdx.x;  // b*S + s
    if (idx == 0) out[LOSS_OFF] = 0.f;
    if (idx >= B_ * S_) return;
    const int b = idx / S_;
    const int s = idx - b * S_;
    float* col = A + (size_t)b * T_ * S_ + s;
    float run = 0.f;
#pragma unroll 10
    for (int t = 0; t < T_; ++t) {
        float a = col[(size_t)t * S_];
        col[(size_t)t * S_] = run;  // cov_shifted
        run += a;
    }
}

// ---------------- K4: final logits + softmax + context + loss ----------------
// 1024 threads; poly-Ec (no exp2) + 4-way common-denominator rcp.
__global__ __launch_bounds__(1024) void k_final(
    const float* __restrict__ EWhT4, const float* __restrict__ EWsb,
    const float* __restrict__ v, const float* __restrict__ w_c,
    const float* __restrict__ cov,
    const unsigned char* __restrict__ mask,
    const float* __restrict__ enc,
    float* __restrict__ out) {
    __shared__ float e_lds[2][512];
    __shared__ float ctxp[2 * H_];
    __shared__ float red[32];
    const int blk = blockIdx.x;
    const int b = blk & 7;
    const int tp = blk >> 3;
    const int bt0 = b * T_ + 2 * tp;
    const int tid = threadIdx.x;
    const int hh = tid >> 9;
    const int s = tid & 511;
    const int bt = bt0 + hh;
    const int lane = tid & 63;
    const int wid = tid >> 6;
    const bool act = (s < S_);

    const float4 vv4 = *reinterpret_cast<const float4*>(v + 4 * lane);
    const float sumv = wave_sum((vv4.x + vv4.y) + (vv4.z + vv4.w));

    float c = 0.f;
    if (act) c = cov[(size_t)bt * S_ + s];
    const float ck = K_EXP * c;

    const float* E = EWsb + (size_t)bt * H_;    // wave-uniform -> s_loads
    float acc = 0.f;
    if (act) {
        const float4* eq = reinterpret_cast<const float4*>(
                               EWhT4 + (size_t)b * HQ_ * S_ * 4) + s;
#pragma unroll 2
        for (int hq = 0; hq < HQ_; ++hq) {
            const float4 Ew = eq[(size_t)hq * S_];
            const int h = 4 * hq;
            const float v0 = v[h], v1 = v[h + 1], v2 = v[h + 2], v3 = v[h + 3];
            float x0 = ck * w_c[h];
            float x1 = ck * w_c[h + 1];
            float x2 = ck * w_c[h + 2];
            float x3 = ck * w_c[h + 3];
            float Ec0 = fmaf(x0, fmaf(x0, fmaf(x0, fmaf(x0, EC4, EC3), EC2), EC1), 1.f);
            float Ec1 = fmaf(x1, fmaf(x1, fmaf(x1, fmaf(x1, EC4, EC3), EC2), EC1), 1.f);
            float Ec2 = fmaf(x2, fmaf(x2, fmaf(x2, fmaf(x2, EC4, EC3), EC2), EC1), 1.f);
            float Ec3 = fmaf(x3, fmaf(x3, fmaf(x3, fmaf(x3, EC4, EC3), EC2), EC1), 1.f);
            float p0 = fmaf(Ew.x * E[h], Ec0, 1.f);
            float p1 = fmaf(Ew.y * E[h + 1], Ec1, 1.f);
            float p2 = fmaf(Ew.z * E[h + 2], Ec2, 1.f);
            float p3 = fmaf(Ew.w * E[h + 3], Ec3, 1.f);
            float p01 = p0 * p1, p23 = p2 * p3;
            float num = fmaf(fmaf(v0, p1, v1 * p0), p23,
                             fmaf(v2, p3, v3 * p2) * p01);
            acc = fmaf(num, __builtin_amdgcn_rcpf(p01 * p23), acc);
        }
    }

    float e = -INFINITY;
    if (act) {
        e = fminf(fmaxf(sumv - 2.f * acc, -MAXL), MAXL);
        if (mask[(size_t)b * S_ + s]) e = -INFINITY;
    }

    float mx = wave_max(e);
    if (lane == 0) red[wid] = mx;
    __syncthreads();
    {
        const float* r8 = red + 8 * hh;
        mx = fmaxf(fmaxf(fmaxf(r8[0], r8[1]), fmaxf(r8[2], r8[3])),
                   fmaxf(fmaxf(r8[4], r8[5]), fmaxf(r8[6], r8[7])));
    }

    float p = act ? __expf(e - mx) : 0.f;
    float sm = wave_sum(p);
    if (lane == 0) red[16 + wid] = sm;
    __syncthreads();
    {
        const float* r8 = red + 16 + 8 * hh;
        sm = ((r8[0] + r8[1]) + (r8[2] + r8[3])) +
             ((r8[4] + r8[5]) + (r8[6] + r8[7]));
    }

    const float a = act ? p * __builtin_amdgcn_rcpf(sm) : 0.f;

    // coverage-loss partial (registers only); red[0..15] free to reuse
    float lp = act ? fminf(a, c) : 0.f;
    lp = wave_sum(lp);
    if (lane == 0) red[wid] = lp;

    if (act) {
        e_lds[hh][s] = a;
        out[AF_OFF + (size_t)bt * S_ + s] = a;
    }
    __syncthreads();

    if (tid == 0) {
        float tot = 0.f;
#pragma unroll
        for (int i = 0; i < 16; ++i) tot += red[i];
        atomicAdd(out + LOSS_OFF, tot * (1.0f / (B_ * T_)));
    }

    // context: 4 threads per h -> (t-select, s-half)
    const int q = tid >> 8;            // 0..3
    const int h = tid & (H_ - 1);
    const int ts = q & 1;              // which t
    const int sb = (q >> 1) * (S_ / 2);
    const float* el = e_lds[ts];
    const float* eb = enc + ((size_t)b * S_ + sb) * H_ + h;
    float q0 = 0.f, q1 = 0.f, q2 = 0.f, q3 = 0.f;
#pragma unroll 5
    for (int j = 0; j < S_ / 2; j += 4) {
        q0 = fmaf(el[sb + j], eb[(size_t)j * H_], q0);
        q1 = fmaf(el[sb + j + 1], eb[(size_t)(j + 1) * H_], q1);
        q2 = fmaf(el[sb + j + 2], eb[(size_t)(j + 2) * H_], q2);
        q3 = fmaf(el[sb + j + 3], eb[(size_t)(j + 3) * H_], q3);
    }
    const float r = (q0 + q1) + (q2 + q3);
    if ((q >> 1) == 0) ctxp[ts * H_ + h] = r;
    __syncthreads();
    if ((q >> 1) == 1)
        out[(size_t)(bt0 + ts) * H_ + h] = ctxp[ts * H_ + h] + r;
}

extern "C" void kernel_launch(void* const* d_in, const int* in_sizes, int n_in,
                              void* d_out, int out_size, void* d_ws, size_t ws_size,
                              hipStream_t stream) {
    const float* dec = (const float*)d_in[0];
    const float* enc = (const float*)d_in[1];
    const unsigned char* mask = (const unsigned char*)d_in[2];
    const float* W_h = (const float*)d_in[3];
    const float* W_s = (const float*)d_in[4];
    const float* w_c = (const float*)d_in[5];
    const float* v = (const float*)d_in[6];
    const float* b_attn = (const float*)d_in[7];

    float* out = (float*)d_out;
    float* ws = (float*)d_ws;
    float* EWhT4 = ws + EWHT_OFF;
    float* EWsb = ws + EWSB_OFF;
    float* Acov = ws + ACOV_OFF;

    const int nb_gemm = (B_ * S_) / ROWS + BT_ / ROWS;  // 400 + 100
    const int nb_pair = B_ * (T_ / 2);                  // 400
    k_gemm<<<nb_gemm, 256, 0, stream>>>(dec, enc, W_h, W_s, b_attn, EWhT4, EWsb);
    k_prelim<<<nb_pair, 1024, 0, stream>>>(EWhT4, EWsb, v, mask, Acov);
    k_cumsum<<<(B_ * S_ + 63) / 64, 64, 0, stream>>>(Acov, out);
    k_final<<<nb_pair, 1024, 0, stream>>>(EWhT4, EWsb, v, w_c, Acov, mask, enc, out);
}